// Round 5
// baseline (317.893 us; speedup 1.0000x reference)
//
#include <hip/hip_runtime.h>

// Problem constants (fixed by reference: B=4, C=512, H=W=64, MID=64)
#define BB 4
#define CD 512
#define NP 4096
#define MID 64
// pbuf row stride: 144 halves = 72 dwords; 72 mod 32 = 8 -> both the half4
// P-writes (bank = 8(col+2w+kt)+2q+j) and b128 P-reads (bank = 8col+16f+4q+j)
// are exact 2-way bank covers = conflict-free (m136: 2-way is free).
#define PSTR 144

typedef _Float16 half8 __attribute__((ext_vector_type(8)));
typedef _Float16 half4 __attribute__((ext_vector_type(4)));
typedef float floatx4 __attribute__((ext_vector_type(4)));

#define LOG2E 1.4426950408889634f

// ---------------------------------------------------------------------------
// Kernel 1: pack wq|wk|wv -> fp16 [640][512], concat biases (fp32 [640]).
// log2(e) folded into wq/bq so softmax uses raw v_exp_f32 (exp2).
// ---------------------------------------------------------------------------
__global__ __launch_bounds__(256) void prep_w(
    const float* __restrict__ wq, const float* __restrict__ wk,
    const float* __restrict__ wv, const float* __restrict__ bq,
    const float* __restrict__ bk, const float* __restrict__ bv,
    _Float16* __restrict__ w_h, float* __restrict__ bias) {
  int idx = blockIdx.x * 256 + threadIdx.x;
  for (int i = idx; i < 640 * 512; i += gridDim.x * 256) {
    int r = i >> 9, c = i & 511;
    float v = (r < 64) ? wq[(r << 9) + c] * LOG2E
            : (r < 128) ? wk[((r - 64) << 9) + c]
                        : wv[((r - 128) << 9) + c];
    w_h[i] = (_Float16)v;
  }
  if (idx < 640) {
    float v = (idx < 64) ? bq[idx] * LOG2E
            : (idx < 128) ? bk[idx - 64]
                          : bv[idx - 128];
    bias[idx] = v;
  }
}

// ---------------------------------------------------------------------------
// Kernel 2: transpose x [b][c][n] fp32 -> xt [b][n][c] fp16 (64x64 LDS tiles)
// ---------------------------------------------------------------------------
__global__ __launch_bounds__(256) void transpose_x(const float* __restrict__ x,
                                                   _Float16* __restrict__ xt) {
  __shared__ float tile[64][65];
  int b = blockIdx.z, c0 = blockIdx.y * 64, n0 = blockIdx.x * 64;
  int t = threadIdx.x;
  const float* xb = x + (size_t)b * CD * NP;
#pragma unroll
  for (int k = 0; k < 16; k++) {
    int cl = k * 4 + (t >> 6);
    int nl = t & 63;
    tile[cl][nl] = xb[(size_t)(c0 + cl) * NP + n0 + nl];
  }
  __syncthreads();
  _Float16* xtb = xt + ((size_t)b * NP + n0) * CD + c0;
#pragma unroll
  for (int k = 0; k < 2; k++) {
    int nl = k * 32 + (t >> 3);
    int cl = (t & 7) * 8;
    half8 pk;
#pragma unroll
    for (int i = 0; i < 8; i++) pk[i] = (_Float16)tile[cl + i][nl];
    *(half8*)(xtb + (size_t)nl * CD + cl) = pk;
  }
}

// ---------------------------------------------------------------------------
// Kernel 3: fused QKV projection. Block = 4 waves, grid (2,64,4):
// 64-position xt tile staged in LDS (XOR-swizzled 16B units), shared by all
// waves; wave w computes 80 W-rows (5 row-tiles x 4 n-tiles).
// ---------------------------------------------------------------------------
__global__ __launch_bounds__(256, 2) void proj_qkv(
    const _Float16* __restrict__ w_h, const float* __restrict__ bias,
    const _Float16* __restrict__ xt, _Float16* __restrict__ q_h,
    _Float16* __restrict__ k_h, _Float16* __restrict__ v_h) {
  __shared__ _Float16 xls[64 * 512];   // 64 KB, XOR-swizzled 16B units
  int t = threadIdx.x, w = t >> 6, lane = t & 63;
  int col = lane & 15, quad = lane >> 4;
  int rbh = blockIdx.x, nb = blockIdx.y, b = blockIdx.z;
  int n0 = nb * 64;
  const _Float16* xtb = xt + ((size_t)b * NP + n0) * CD;

#pragma unroll
  for (int j = 0; j < 16; j++) {
    int u = t + j * 256;
    int row = u >> 6, un = u & 63;
    *(half8*)(xls + row * 512 + ((un ^ (row & 7)) << 3)) =
        *(const half8*)(xtb + (size_t)row * CD + un * 8);
  }
  __syncthreads();

  int rw = rbh * 320 + w * 80;
  floatx4 acc[5][4] = {};
  for (int c = 0; c < CD; c += 32) {
    int cu = c >> 3;
    half8 a[5], bf[4];
#pragma unroll
    for (int i = 0; i < 5; i++)
      a[i] = *(const half8*)(w_h + (size_t)(rw + i * 16 + col) * CD + c + quad * 8);
#pragma unroll
    for (int j = 0; j < 4; j++) {
      int row = j * 16 + col;
      bf[j] = *(const half8*)(xls + row * 512 + (((cu + quad) ^ (row & 7)) << 3));
    }
#pragma unroll
    for (int i = 0; i < 5; i++)
#pragma unroll
      for (int j = 0; j < 4; j++)
        acc[i][j] = __builtin_amdgcn_mfma_f32_16x16x32_f16(a[i], bf[j], acc[i][j], 0, 0, 0);
  }

#pragma unroll
  for (int i = 0; i < 5; i++) {
    int r0 = rw + i * 16;
    float bi[4];
#pragma unroll
    for (int rr = 0; rr < 4; rr++) bi[rr] = bias[r0 + quad * 4 + rr];
    if (r0 < 128) {
      _Float16* dst = (r0 < 64 ? q_h + (size_t)b * NP * MID + r0
                               : k_h + (size_t)b * NP * MID + (r0 - 64));
#pragma unroll
      for (int j = 0; j < 4; j++) {
        int n = n0 + j * 16 + col;
        half4 pk;
#pragma unroll
        for (int rr = 0; rr < 4; rr++) pk[rr] = (_Float16)(acc[i][j][rr] + bi[rr]);
        *(half4*)(dst + (size_t)n * MID + quad * 4) = pk;
      }
    } else {
      int dbase = r0 - 128 + quad * 4;
#pragma unroll
      for (int j = 0; j < 4; j++) {
        int n = n0 + j * 16 + col;
#pragma unroll
        for (int rr = 0; rr < 4; rr++)
          v_h[((size_t)b * CD + dbase + rr) * NP + n] =
              (_Float16)(acc[i][j][rr] + bi[rr]);
      }
    }
  }
}

// ---------------------------------------------------------------------------
// Kernel 4: row max of S (log2-domain). Block = 32 q; 4 waves split the 4096
// keys 4-way. Grid (128, B).
// ---------------------------------------------------------------------------
__global__ __launch_bounds__(256) void rowmax(const _Float16* __restrict__ q_h,
                                              const _Float16* __restrict__ k_h,
                                              float* __restrict__ M) {
  int qb = blockIdx.x, b = blockIdx.y;
  int t = threadIdx.x, w = t >> 6, lane = t & 63;
  int col = lane & 15, quad = lane >> 4;
  int q0 = qb * 32;
  const _Float16* qp = q_h + ((size_t)b * NP + q0) * MID;
  half8 bq[2][2];
#pragma unroll
  for (int qt = 0; qt < 2; qt++)
#pragma unroll
    for (int h = 0; h < 2; h++)
      bq[qt][h] = *(const half8*)(qp + (size_t)(qt * 16 + col) * MID + h * 32 + quad * 8);
  const _Float16* kp = k_h + ((size_t)b * NP + (size_t)w * 1024) * MID;
  float m[2] = {-1e30f, -1e30f};
#pragma unroll 4
  for (int n = 0; n < 1024; n += 16) {
    half8 ak0 = *(const half8*)(kp + (size_t)(n + col) * MID + quad * 8);
    half8 ak1 = *(const half8*)(kp + (size_t)(n + col) * MID + 32 + quad * 8);
#pragma unroll
    for (int qt = 0; qt < 2; qt++) {
      floatx4 s = {};
      s = __builtin_amdgcn_mfma_f32_16x16x32_f16(ak0, bq[qt][0], s, 0, 0, 0);
      s = __builtin_amdgcn_mfma_f32_16x16x32_f16(ak1, bq[qt][1], s, 0, 0, 0);
      m[qt] = fmaxf(m[qt], fmaxf(fmaxf(s[0], s[1]), fmaxf(s[2], s[3])));
    }
  }
  __shared__ float red[4][2][16];
#pragma unroll
  for (int qt = 0; qt < 2; qt++) {
    m[qt] = fmaxf(m[qt], __shfl_xor(m[qt], 16));
    m[qt] = fmaxf(m[qt], __shfl_xor(m[qt], 32));
  }
  if (quad == 0) {
    red[w][0][col] = m[0];
    red[w][1][col] = m[1];
  }
  __syncthreads();
  if (t < 32) {
    int qt = t >> 4, c = t & 15;
    float mm = fmaxf(fmaxf(red[0][qt][c], red[1][qt][c]),
                     fmaxf(red[2][qt][c], red[3][qt][c]));
    M[(size_t)b * NP + q0 + t] = mm;
  }
}

// ---------------------------------------------------------------------------
// Kernel 5: attention + PV + epilogue, v5.
// Grid 512 = b(4) x ds(2: 256 d) x qb(64); block = 4 waves = 64q x 256d.
// 128-key chunks (32 barriers): wave w scores ITS 32 keys vs all 64 q into
// double-buffered pbuf (PSTR=144 -> 2-way banks on writes AND b128 reads);
// ONE barrier; PV for its private 64d x 64q over the full 128-key chunk.
// K for chunk ci+1 explicitly double-buffered in regs (no cold load at
// phase head); V frags for chunk ci issued before the barrier (drain covers
// them). acc[4][4] static -> no spill.
// ---------------------------------------------------------------------------
__global__ __launch_bounds__(256, 2) void attn_pv(
    const _Float16* __restrict__ q_h, const _Float16* __restrict__ k_h,
    const _Float16* __restrict__ v_h, const float* __restrict__ M,
    const float* __restrict__ x, const float* __restrict__ alpha_p,
    float* __restrict__ out) {
  int bid = blockIdx.x;
  int combo = bid & 7;               // -> XCD via round-robin dispatch
  int b = combo >> 1, ds = combo & 1;
  int qb = bid >> 3;                 // 0..63
  int q0 = qb * 64, d0 = ds * 256;

  int t = threadIdx.x, w = t >> 6, lane = t & 63;
  int col = lane & 15, quad = lane >> 4;

  __shared__ _Float16 pbuf[2][64 * PSTR];   // 36.9 KB double-buffered P
  __shared__ float lred[4][4][16];
  __shared__ float lfin[64];

  const _Float16* qp = q_h + ((size_t)b * NP + q0) * MID;
  half8 bq[4][2];
#pragma unroll
  for (int qt = 0; qt < 4; qt++)
#pragma unroll
    for (int h = 0; h < 2; h++)
      bq[qt][h] = *(const half8*)(qp + (size_t)(qt * 16 + col) * MID + h * 32 + quad * 8);
  float Mq[4];
#pragma unroll
  for (int qt = 0; qt < 4; qt++) Mq[qt] = M[(size_t)b * NP + q0 + qt * 16 + col];

  const _Float16* kp = k_h + (size_t)b * NP * MID;
  const _Float16* vp = v_h + ((size_t)(b * CD + d0) + w * 64) * NP;

  floatx4 acc[4][4] = {};            // [dt][qt] = 64 VGPRs, static indices
  float lp[4] = {0.f, 0.f, 0.f, 0.f};

  // preload K for chunk 0 (this wave's 32 keys)
  half8 ak[2][2];
#pragma unroll
  for (int kt = 0; kt < 2; kt++) {
    const _Float16* kr = kp + (size_t)(w * 32 + kt * 16 + col) * MID;
    ak[kt][0] = *(const half8*)(kr + quad * 8);
    ak[kt][1] = *(const half8*)(kr + 32 + quad * 8);
  }

  for (int ci = 0; ci < 32; ci++) {
    int nc = ci * 128;
    _Float16* pb = pbuf[ci & 1];

    // V frags for this chunk (consumed after the barrier; drain covers them)
    half8 av[4][4];
#pragma unroll
    for (int f = 0; f < 4; f++)
#pragma unroll
      for (int dt = 0; dt < 4; dt++)
        av[f][dt] = *(const half8*)(vp + (size_t)(dt * 16 + col) * NP + nc + f * 32 + quad * 8);

    // K for next chunk (register double-buffer)
    half8 nk[2][2];
    {
      int ncn = ((ci + 1) & 31) * 128;
      const _Float16* kr0 = kp + (size_t)(ncn + w * 32 + col) * MID;
      nk[0][0] = *(const half8*)(kr0 + quad * 8);
      nk[0][1] = *(const half8*)(kr0 + 32 + quad * 8);
      const _Float16* kr1 = kp + (size_t)(ncn + w * 32 + 16 + col) * MID;
      nk[1][0] = *(const half8*)(kr1 + quad * 8);
      nk[1][1] = *(const half8*)(kr1 + 32 + quad * 8);
    }

    // ---- score phase: this wave's 32 keys vs all 64 q ----
#pragma unroll
    for (int kt = 0; kt < 2; kt++)
#pragma unroll
      for (int qt = 0; qt < 4; qt++) {
        floatx4 s = {};
        s = __builtin_amdgcn_mfma_f32_16x16x32_f16(ak[kt][0], bq[qt][0], s, 0, 0, 0);
        s = __builtin_amdgcn_mfma_f32_16x16x32_f16(ak[kt][1], bq[qt][1], s, 0, 0, 0);
        half4 pk;
#pragma unroll
        for (int r = 0; r < 4; r++) {
          float p = exp2f(s[r] - Mq[qt]);
          lp[qt] += p;
          pk[r] = (_Float16)p;
        }
        *(half4*)(pb + (qt * 16 + col) * PSTR + w * 32 + kt * 16 + quad * 4) = pk;
      }
    __syncthreads();

    // ---- PV phase: private 64d x 64q over the full 128-key chunk ----
#pragma unroll
    for (int f = 0; f < 4; f++) {
      half8 bp[4];
#pragma unroll
      for (int qt = 0; qt < 4; qt++)
        bp[qt] = *(const half8*)(pb + (qt * 16 + col) * PSTR + f * 32 + quad * 8);
#pragma unroll
      for (int dt = 0; dt < 4; dt++)
#pragma unroll
        for (int qt = 0; qt < 4; qt++)
          acc[dt][qt] = __builtin_amdgcn_mfma_f32_16x16x32_f16(av[f][dt], bp[qt], acc[dt][qt], 0, 0, 0);
    }

    ak[0][0] = nk[0][0]; ak[0][1] = nk[0][1];
    ak[1][0] = nk[1][0]; ak[1][1] = nk[1][1];
  }

  // l: reduce across quads (keys) within wave, then across waves via LDS
#pragma unroll
  for (int qt = 0; qt < 4; qt++) {
    lp[qt] += __shfl_xor(lp[qt], 16);
    lp[qt] += __shfl_xor(lp[qt], 32);
    if (quad == 0) lred[w][qt][col] = lp[qt];
  }
  __syncthreads();
  if (t < 64) {
    int qt = t >> 4, c = t & 15;
    float l = lred[0][qt][c] + lred[1][qt][c] + lred[2][qt][c] + lred[3][qt][c];
    lfin[t] = alpha_p[0] / l;
  }
  __syncthreads();

  // epilogue: fused alpha/l scale + residual; 64B-segment coalesced stores
  const float* xp = x + ((size_t)(b * CD + d0) + w * 64) * NP;
  float* op = out + ((size_t)(b * CD + d0) + w * 64) * NP;
#pragma unroll
  for (int dt = 0; dt < 4; dt++)
#pragma unroll
    for (int qt = 0; qt < 4; qt++) {
      float linv = lfin[qt * 16 + col];
#pragma unroll
      for (int r = 0; r < 4; r++) {
        size_t o = (size_t)(dt * 16 + quad * 4 + r) * NP + q0 + qt * 16 + col;
        op[o] = acc[dt][qt][r] * linv + xp[o];
      }
    }
}

// ---------------------------------------------------------------------------
extern "C" void kernel_launch(void* const* d_in, const int* in_sizes, int n_in,
                              void* d_out, int out_size, void* d_ws, size_t ws_size,
                              hipStream_t stream) {
  const float* x     = (const float*)d_in[0];
  const float* wq    = (const float*)d_in[1];
  const float* bq    = (const float*)d_in[2];
  const float* wk    = (const float*)d_in[3];
  const float* bk    = (const float*)d_in[4];
  const float* wv    = (const float*)d_in[5];
  const float* bv    = (const float*)d_in[6];
  const float* alpha = (const float*)d_in[7];
  float* out = (float*)d_out;

  char* ws = (char*)d_ws;
  _Float16* w_h  = (_Float16*)(ws);                    // 640*512*2   = 655360
  float*    bias = (float*)(ws + 655360);              // 640*4       = 2560
  float*    Mbuf = (float*)(ws + 657920);              // 4*4096*4    = 65536
  _Float16* xt   = (_Float16*)(ws + 723456);           // 4*4096*512*2= 16777216
  _Float16* q_h  = (_Float16*)(ws + 17500672);         // 4*4096*64*2 = 2097152
  _Float16* k_h  = (_Float16*)(ws + 19597824);         // 4*4096*64*2 = 2097152
  _Float16* v_h  = (_Float16*)(ws + 21694976);         // 4*512*4096*2= 16777216

  prep_w<<<1280, 256, 0, stream>>>(wq, wk, wv, bq, bk, bv, w_h, bias);
  transpose_x<<<dim3(64, 8, BB), 256, 0, stream>>>(x, xt);
  proj_qkv<<<dim3(2, 64, BB), 256, 0, stream>>>(w_h, bias, xt, q_h, k_h, v_h);
  rowmax<<<dim3(128, BB), 256, 0, stream>>>(q_h, k_h, Mbuf);
  attn_pv<<<512, 256, 0, stream>>>(q_h, k_h, v_h, Mbuf, x, alpha, out);
}